// Round 6
// baseline (314.366 us; speedup 1.0000x reference)
//
#include <hip/hip_runtime.h>
#include <math.h>

// LoRA-MLP, fp32 in/out. Fold rank-16 LoRA into weights (K=1), then two
// bf16 MFMA GEMMs: h = gelu(x@W1eff^T + b1); out = h@W2eff^T + b2.
#define M_ROWS 12608   // 64*197
#define D_DIM  768
#define H_DIM  3072

typedef __bf16 bf16_t;
typedef __bf16 bf16x8 __attribute__((ext_vector_type(8)));
typedef float  f32x4  __attribute__((ext_vector_type(4)));

__device__ __forceinline__ void gl2lds16(const bf16_t* g, bf16_t* l) {
  __builtin_amdgcn_global_load_lds(
      (__attribute__((address_space(1))) void*)g,
      (__attribute__((address_space(3))) void*)l,
      16, 0, 0);
}

// Fast GELU via sigmoid form of the tanh approximation:
// gelu(v) ~= v * sigmoid(1.5957691*(v + 0.044715 v^3)); |dev from exact| <= ~3e-4.
__device__ __forceinline__ float gelu_fast(float v) {
  float v2 = v * v;
  float z = v * fmaf(0.044715f, v2, 1.0f);
  float e = __expf(-1.5957691216057308f * z);
  return v * __builtin_amdgcn_rcpf(1.0f + e);
}

__global__ void cast_f32_bf16_kernel(const float* __restrict__ in,
                                     bf16_t* __restrict__ out, long n) {
  long i = ((long)blockIdx.x * 256 + threadIdx.x) * 4;
  if (i + 3 < n) {
    float4 v = *(const float4*)(in + i);
    out[i + 0] = (bf16_t)v.x; out[i + 1] = (bf16_t)v.y;
    out[i + 2] = (bf16_t)v.z; out[i + 3] = (bf16_t)v.w;
  } else {
    for (; i < n; ++i) out[i] = (bf16_t)in[i];
  }
}

// Weff[o][i] = W[o][i] + sum_r Bm[o][r]*A[r][i]  (fp32 in, bf16 out)
__global__ void fold_lora_kernel(const float* __restrict__ W,
                                 const float* __restrict__ A,
                                 const float* __restrict__ Bm,
                                 bf16_t* __restrict__ Weff,
                                 int OUT, int IN) {
  long idx = (long)blockIdx.x * 256 + threadIdx.x;
  if (idx >= (long)OUT * IN) return;
  int o = (int)(idx / IN);
  int i = (int)(idx - (long)o * IN);
  float s = W[idx];
#pragma unroll
  for (int r = 0; r < 16; ++r)
    s += Bm[o * 16 + r] * A[r * IN + i];
  Weff[idx] = (bf16_t)s;
}

// Unified GEMM: C[m][n] = act(sum_k A[m][k]*B[n][k] + bias[n]).
// 128x128 tile, 4 waves 2x2 (64x64 wave tile, 4x4 acc), BK=32,
// DOUBLE-BUFFERED LDS via global_load_lds: per iter {barrier; issue it+1 ->
// other buffer; compute it}. The barrier's vmcnt-drain then waits on loads
// that had a full compute phase in flight -> staging latency hidden per-wave.
// XOR-swizzled LDS (chunk (row,kc) at slot kc^((row>>1)&3)): 0 bank conflicts.
// XCD-banded 1-D grid. GELU path: LDS-transpose epilogue, 64B bf16 stores.
template <bool GELU, typename OutT, int SMEM_BYTES>
__global__ __launch_bounds__(256, 3) void gemm_kernel(
    const bf16_t* __restrict__ Amat, const bf16_t* __restrict__ Bmat,
    const float* __restrict__ bias, OutT* __restrict__ Cmat,
    int Mrows, int Ncols, int Kd, int nColT, int nRowT) {
  __shared__ char smem[SMEM_BYTES];
  bf16_t* lds = (bf16_t*)smem;     // two buffers of 8192 elements (16 KB each):
                                   //   [A 4096 el][B 4096 el] per buffer
  float* sT = (float*)smem;        // GELU epilogue scratch [64][132] f32

  // XCD-banded swizzle: consecutive blocks on one XCD sweep columns for a
  // fixed row-band -> A-row-slice L2-resident per XCD.
  const int xcd = blockIdx.x & 7, tswz = blockIdx.x >> 3;
  const int colb = tswz % nColT, rband = tswz / nColT;
  const int rowb = rband * 8 + xcd;
  if (rowb >= nRowT) return;
  const int row0 = rowb * 128, col0 = colb * 128;

  const int tid = threadIdx.x, lane = tid & 63, wave = tid >> 6;
  const int wm = wave & 1, wn = wave >> 1;

  // staging: A tile = 512 16B-chunks (2/thread), B same. chunk c -> row c>>2,
  // LDS slot kc=c&3 holds global k-chunk (c&3)^((row>>1)&3).
  const bf16_t* gA[2]; const bf16_t* gB[2];
  int stA[2], stB[2];
#pragma unroll
  for (int q = 0; q < 2; ++q) {
    int c = tid + q * 256;
    int r = c >> 2;
    int kcg = (c & 3) ^ ((r >> 1) & 3);
    int ra = row0 + r; if (ra > Mrows - 1) ra = Mrows - 1;  // M-edge clamp
    gA[q] = Amat + (size_t)ra * Kd + kcg * 8;
    stA[q] = (q * 256 + wave * 64) * 8;
    gB[q] = Bmat + (size_t)(col0 + r) * Kd + kcg * 8;
    stB[q] = 4096 + (q * 256 + wave * 64) * 8;
  }

  // fragment element-offsets within a buffer (swizzle-aware)
  const int rl = lane & 15, kc = lane >> 4;
  int aoffs[4], boffs[4];
#pragma unroll
  for (int i = 0; i < 4; ++i) {
    int ra = wm * 64 + i * 16 + rl;
    int rb = wn * 64 + i * 16 + rl;
    aoffs[i] = ra * 32 + ((kc ^ ((ra >> 1) & 3)) * 8);
    boffs[i] = 4096 + rb * 32 + ((kc ^ ((rb >> 1) & 3)) * 8);
  }

  auto issue = [&](int par) {
    bf16_t* bb = lds + par * 8192;
    gl2lds16(gA[0], bb + stA[0]); gl2lds16(gA[1], bb + stA[1]);
    gl2lds16(gB[0], bb + stB[0] - 4096 + 4096); gl2lds16(gB[1], bb + stB[1] - 4096 + 4096);
    gA[0] += 32; gA[1] += 32; gB[0] += 32; gB[1] += 32;
  };

  f32x4 acc[4][4] = {};
  const int iters = Kd / 32;

  issue(0);  // prologue
  for (int it = 0; it < iters; ++it) {
    __syncthreads();                    // drains loads for buffer it&1
    if (it + 1 < iters) issue((it + 1) & 1);  // prefetch flies during compute
    const bf16_t* buf = lds + (it & 1) * 8192;
    bf16x8 af[4], bfr[4];
#pragma unroll
    for (int i = 0; i < 4; ++i) af[i] = *(const bf16x8*)(buf + aoffs[i]);
#pragma unroll
    for (int i = 0; i < 4; ++i) bfr[i] = *(const bf16x8*)(buf + boffs[i]);
#pragma unroll
    for (int mi = 0; mi < 4; ++mi)
#pragma unroll
      for (int ni = 0; ni < 4; ++ni)
        acc[mi][ni] = __builtin_amdgcn_mfma_f32_16x16x32_bf16(
            af[mi], bfr[ni], acc[mi][ni], 0, 0, 0);
  }

  // epilogue. C/D lane layout: col=lane&15, row=(lane>>4)*4+reg [m89-verified]
  const int crow = (lane >> 4) * 4, ccol = lane & 15;
  if constexpr (GELU) {
    __syncthreads();  // all waves done with LDS buffers before sT reuse
#pragma unroll
    for (int p = 0; p < 2; ++p) {
#pragma unroll
      for (int s = 0; s < 2; ++s) {
        int mi = 2 * p + s;
#pragma unroll
        for (int ni = 0; ni < 4; ++ni)
#pragma unroll
          for (int r = 0; r < 4; ++r)
            sT[(wm * 32 + s * 16 + crow + r) * 132 + wn * 64 + ni * 16 + ccol] =
                acc[mi][ni][r];
      }
      __syncthreads();
      const int erow = tid >> 2, eseg = tid & 3;
      const int grow = row0 + (erow >> 5) * 64 + (2 * p + ((erow >> 4) & 1)) * 16 + (erow & 15);
      if (grow < Mrows) {
        const float* src = sT + erow * 132 + eseg * 32;
        const float* bsrc = bias + col0 + eseg * 32;
        bf16_t ov[32];
#pragma unroll
        for (int i = 0; i < 32; ++i)
          ov[i] = (bf16_t)gelu_fast(src[i] + bsrc[i]);
        bf16_t* dst = (bf16_t*)Cmat + (size_t)grow * Ncols + col0 + eseg * 32;
#pragma unroll
        for (int k = 0; k < 4; ++k)
          *(bf16x8*)(dst + k * 8) = *(bf16x8*)(ov + k * 8);
      }
      __syncthreads();
    }
  } else {
#pragma unroll
    for (int ni = 0; ni < 4; ++ni) {
      const int gc = col0 + wn * 64 + ni * 16 + ccol;
      const float bv = bias[gc];
#pragma unroll
      for (int mi = 0; mi < 4; ++mi) {
        const int gr = row0 + wm * 64 + mi * 16 + crow;
#pragma unroll
        for (int r = 0; r < 4; ++r) {
          const int row = gr + r;
          if (row < Mrows)
            Cmat[(size_t)row * Ncols + gc] = acc[mi][ni][r] + bv;
        }
      }
    }
  }
}

extern "C" void kernel_launch(void* const* d_in, const int* in_sizes, int n_in,
                              void* d_out, int out_size, void* d_ws, size_t ws_size,
                              hipStream_t stream) {
  const float* x  = (const float*)d_in[0];
  const float* W1 = (const float*)d_in[1];
  const float* b1 = (const float*)d_in[2];
  const float* A1 = (const float*)d_in[3];
  const float* B1 = (const float*)d_in[4];
  const float* W2 = (const float*)d_in[5];
  const float* b2 = (const float*)d_in[6];
  const float* A2 = (const float*)d_in[7];
  const float* B2 = (const float*)d_in[8];
  float* out = (float*)d_out;

  char* ws = (char*)d_ws;
  bf16_t* xb    = (bf16_t*)ws;                             // 19,365,888 B (pad)
  bf16_t* W1eff = (bf16_t*)(ws + 19366144);                //  4,718,592 B
  bf16_t* W2eff = (bf16_t*)(ws + 19366144 + 4718592);      //  4,718,592 B
  bf16_t* hbuf  = (bf16_t*)(ws + 19366144 + 2 * 4718592);  // 77,463,552 B

  const long nx = (long)M_ROWS * D_DIM;
  cast_f32_bf16_kernel<<<(int)((nx / 4 + 255) / 256), 256, 0, stream>>>(x, xb, nx);

  const int foldBlocks = (H_DIM * D_DIM + 255) / 256;
  fold_lora_kernel<<<foldBlocks, 256, 0, stream>>>(W1, A1, B1, W1eff, H_DIM, D_DIM);
  fold_lora_kernel<<<foldBlocks, 256, 0, stream>>>(W2, A2, B2, W2eff, D_DIM, H_DIM);

  // GEMM1: 99 row-tiles x 24 col-tiles, XCD-banded: ceil(99/8)=13 rbands -> 2496
  gemm_kernel<true, bf16_t, 34048><<<2496, 256, 0, stream>>>(
      xb, W1eff, b1, hbuf, M_ROWS, H_DIM, D_DIM, 24, 99);
  // GEMM2: 99 row-tiles x 6 col-tiles -> 13*6*8 = 624
  gemm_kernel<false, float, 32768><<<624, 256, 0, stream>>>(
      hbuf, W2eff, b2, out, M_ROWS, D_DIM, H_DIM, 6, 99);
}

// Round 7
// 293.664 us; speedup vs baseline: 1.0705x; 1.0705x over previous
//
#include <hip/hip_runtime.h>
#include <math.h>

// LoRA-MLP, fp32 in/out. Fold rank-16 LoRA into weights (K=1), then two
// bf16 MFMA GEMMs: h = gelu(x@W1eff^T + b1); out = h@W2eff^T + b2.
#define M_ROWS 12608   // 64*197
#define D_DIM  768
#define H_DIM  3072

typedef __bf16 bf16_t;
typedef __bf16 bf16x8 __attribute__((ext_vector_type(8)));
typedef float  f32x4  __attribute__((ext_vector_type(4)));

// Fast GELU via sigmoid form of the tanh approximation (validated r6,
// absmax contribution ~3e-4 << threshold).
__device__ __forceinline__ float gelu_fast(float v) {
  float v2 = v * v;
  float z = v * fmaf(0.044715f, v2, 1.0f);
  float e = __expf(-1.5957691216057308f * z);
  return v * __builtin_amdgcn_rcpf(1.0f + e);
}

__global__ void cast_f32_bf16_kernel(const float* __restrict__ in,
                                     bf16_t* __restrict__ out, long n) {
  long i = ((long)blockIdx.x * 256 + threadIdx.x) * 4;
  if (i + 3 < n) {
    float4 v = *(const float4*)(in + i);
    out[i + 0] = (bf16_t)v.x; out[i + 1] = (bf16_t)v.y;
    out[i + 2] = (bf16_t)v.z; out[i + 3] = (bf16_t)v.w;
  } else {
    for (; i < n; ++i) out[i] = (bf16_t)in[i];
  }
}

// Weff[o][i] = W[o][i] + sum_r Bm[o][r]*A[r][i]  (fp32 in, bf16 out)
__global__ void fold_lora_kernel(const float* __restrict__ W,
                                 const float* __restrict__ A,
                                 const float* __restrict__ Bm,
                                 bf16_t* __restrict__ Weff,
                                 int OUT, int IN) {
  long idx = (long)blockIdx.x * 256 + threadIdx.x;
  if (idx >= (long)OUT * IN) return;
  int o = (int)(idx / IN);
  int i = (int)(idx - (long)o * IN);
  float s = W[idx];
#pragma unroll
  for (int r = 0; r < 16; ++r)
    s += Bm[o * 16 + r] * A[r * IN + i];
  Weff[idx] = (bf16_t)s;
}

// Unified GEMM: C[m][n] = act(sum_k A[m][k]*B[n][k] + bias[n]).
// 128x128 tile, 4 waves 2x2 (64x64 wave tile, 4x4 acc of 16x16x32), BK=64.
// REGISTER-STAGED pipeline, single LDS buffer: loads for tile it+1 are issued
// to VGPRs BEFORE computing tile it; the vmcnt wait lands before the ds_write
// AFTER compute -> one full compute phase (~400cyc) of latency cover, and
// barriers only order LDS traffic. XOR-swizzle: row r global k-chunk kk(16B)
// stored at slot kk^(r&7) -> <=2-way bank aliasing everywhere (free).
// SCHED 1 (GEMM1): per XCD sweep rbands fast per col (A-band L2-resident).
// SCHED 2 (GEMM2): 6 cols split over two 4-XCD groups; 3 cols fast per rband
// (W 3-col group L2-resident).
template <bool GELU, typename OutT, int SCHED, int SMEM_BYTES>
__global__ __launch_bounds__(256, 3) void gemm_kernel(
    const bf16_t* __restrict__ Amat, const bf16_t* __restrict__ Bmat,
    const float* __restrict__ bias, OutT* __restrict__ Cmat,
    int Mrows, int Ncols, int Kd) {
  __shared__ char smem[SMEM_BYTES];
  bf16_t* lds = (bf16_t*)smem;   // A: elements [0,8192), B: [8192,16384)
  float* sT = (float*)smem;      // GELU epilogue scratch [64][132] f32

  int rowb, colb;
  const int xcd = blockIdx.x & 7, t = blockIdx.x >> 3;
  if (SCHED == 1) {              // 24 cols x 13 rbands per XCD, rband-fast
    colb = t / 13;
    rowb = (t % 13) * 8 + xcd;
    if (rowb >= 99) return;
  } else {                       // 3 cols x 25 rbands per XCD, col-fast
    rowb = (t / 3) * 4 + (xcd & 3);
    if (rowb >= 99) return;
    colb = (xcd >> 2) * 3 + (t % 3);
  }
  const int row0 = rowb * 128, col0 = colb * 128;

  const int tid = threadIdx.x, lane = tid & 63, wave = tid >> 6;
  const int wm = wave & 1, wn = wave >> 1;

  // staging: A tile [128][64] = 1024 16B-chunks, 4/thread; B same.
  // chunk c -> row c>>3, global k-chunk kkg = c&7, LDS slot kkg^(row&7).
  const bf16_t* gA[4]; const bf16_t* gB[4];
  int offA[4], offB[4];
#pragma unroll
  for (int q = 0; q < 4; ++q) {
    int c = tid + q * 256;
    int r = c >> 3, kkg = c & 7;
    int ra = row0 + r; if (ra > Mrows - 1) ra = Mrows - 1;  // M-edge clamp
    gA[q] = Amat + (size_t)ra * Kd + kkg * 8;
    offA[q] = r * 64 + (kkg ^ (r & 7)) * 8;
    gB[q] = Bmat + (size_t)(col0 + r) * Kd + kkg * 8;
    offB[q] = 8192 + r * 64 + (kkg ^ (r & 7)) * 8;
  }

  // fragment element-offsets for ks=0 (ks=1: ^32): global chunk ks*4+kc at
  // slot (ks*4+kc)^(r&7); offsets' slot bits are 3..5 so ks toggles bit 5.
  const int rl = lane & 15, kc = lane >> 4;
  int aoffs[4], boffs[4];
#pragma unroll
  for (int i = 0; i < 4; ++i) {
    int ra = wm * 64 + i * 16 + rl;
    int rb = wn * 64 + i * 16 + rl;
    aoffs[i] = ra * 64 + ((kc ^ (ra & 7)) * 8);
    boffs[i] = 8192 + rb * 64 + ((kc ^ (rb & 7)) * 8);
  }

  f32x4 acc[4][4] = {};
  f32x4 pA[4], pB[4];
  const int iters = Kd / 64;

  // prologue: tile 0 -> regs -> LDS
#pragma unroll
  for (int q = 0; q < 4; ++q) {
    pA[q] = *(const f32x4*)gA[q]; pB[q] = *(const f32x4*)gB[q];
    gA[q] += 64; gB[q] += 64;
  }
#pragma unroll
  for (int q = 0; q < 4; ++q) {
    *(f32x4*)(lds + offA[q]) = pA[q];
    *(f32x4*)(lds + offB[q]) = pB[q];
  }
  __syncthreads();

  for (int it = 0; it < iters; ++it) {
    const bool more = (it + 1 < iters);
    if (more) {
#pragma unroll
      for (int q = 0; q < 4; ++q) {          // prefetch it+1 into regs
        pA[q] = *(const f32x4*)gA[q]; pB[q] = *(const f32x4*)gB[q];
        gA[q] += 64; gB[q] += 64;
      }
    }
#pragma unroll
    for (int ks = 0; ks < 2; ++ks) {         // compute it from LDS
      bf16x8 af[4], bfr[4];
#pragma unroll
      for (int i = 0; i < 4; ++i) af[i] = *(const bf16x8*)(lds + (aoffs[i] ^ (ks * 32)));
#pragma unroll
      for (int i = 0; i < 4; ++i) bfr[i] = *(const bf16x8*)(lds + (boffs[i] ^ (ks * 32)));
#pragma unroll
      for (int mi = 0; mi < 4; ++mi)
#pragma unroll
        for (int ni = 0; ni < 4; ++ni)
          acc[mi][ni] = __builtin_amdgcn_mfma_f32_16x16x32_bf16(
              af[mi], bfr[ni], acc[mi][ni], 0, 0, 0);
    }
    if (more) {
      __syncthreads();                       // all waves done reading LDS
#pragma unroll
      for (int q = 0; q < 4; ++q) {          // vmcnt wait lands here (covered)
        *(f32x4*)(lds + offA[q]) = pA[q];
        *(f32x4*)(lds + offB[q]) = pB[q];
      }
      __syncthreads();                       // writes visible
    }
  }

  // epilogue. C/D lane layout: col=lane&15, row=(lane>>4)*4+reg [m89-verified]
  const int crow = (lane >> 4) * 4, ccol = lane & 15;
  if constexpr (GELU) {
    __syncthreads();  // all waves done with LDS tiles before sT reuse
#pragma unroll
    for (int p = 0; p < 2; ++p) {
#pragma unroll
      for (int s = 0; s < 2; ++s) {
        int mi = 2 * p + s;
#pragma unroll
        for (int ni = 0; ni < 4; ++ni)
#pragma unroll
          for (int r = 0; r < 4; ++r)
            sT[(wm * 32 + s * 16 + crow + r) * 132 + wn * 64 + ni * 16 + ccol] =
                acc[mi][ni][r];
      }
      __syncthreads();
      const int erow = tid >> 2, eseg = tid & 3;
      const int grow = row0 + (erow >> 5) * 64 + (2 * p + ((erow >> 4) & 1)) * 16 + (erow & 15);
      if (grow < Mrows) {
        const float* src = sT + erow * 132 + eseg * 32;
        const float* bsrc = bias + col0 + eseg * 32;
        bf16_t ov[32];
#pragma unroll
        for (int i = 0; i < 32; ++i)
          ov[i] = (bf16_t)gelu_fast(src[i] + bsrc[i]);
        bf16_t* dst = (bf16_t*)Cmat + (size_t)grow * Ncols + col0 + eseg * 32;
#pragma unroll
        for (int k = 0; k < 4; ++k)
          *(bf16x8*)(dst + k * 8) = *(bf16x8*)(ov + k * 8);
      }
      __syncthreads();
    }
  } else {
#pragma unroll
    for (int ni = 0; ni < 4; ++ni) {
      const int gc = col0 + wn * 64 + ni * 16 + ccol;
      const float bv = bias[gc];
#pragma unroll
      for (int mi = 0; mi < 4; ++mi) {
        const int gr = row0 + wm * 64 + mi * 16 + crow;
#pragma unroll
        for (int r = 0; r < 4; ++r) {
          const int row = gr + r;
          if (row < Mrows)
            Cmat[(size_t)row * Ncols + gc] = acc[mi][ni][r] + bv;
        }
      }
    }
  }
}

extern "C" void kernel_launch(void* const* d_in, const int* in_sizes, int n_in,
                              void* d_out, int out_size, void* d_ws, size_t ws_size,
                              hipStream_t stream) {
  const float* x  = (const float*)d_in[0];
  const float* W1 = (const float*)d_in[1];
  const float* b1 = (const float*)d_in[2];
  const float* A1 = (const float*)d_in[3];
  const float* B1 = (const float*)d_in[4];
  const float* W2 = (const float*)d_in[5];
  const float* b2 = (const float*)d_in[6];
  const float* A2 = (const float*)d_in[7];
  const float* B2 = (const float*)d_in[8];
  float* out = (float*)d_out;

  char* ws = (char*)d_ws;
  bf16_t* xb    = (bf16_t*)ws;                             // 19,365,888 B (pad)
  bf16_t* W1eff = (bf16_t*)(ws + 19366144);                //  4,718,592 B
  bf16_t* W2eff = (bf16_t*)(ws + 19366144 + 4718592);      //  4,718,592 B
  bf16_t* hbuf  = (bf16_t*)(ws + 19366144 + 2 * 4718592);  // 77,463,552 B

  const long nx = (long)M_ROWS * D_DIM;
  cast_f32_bf16_kernel<<<(int)((nx / 4 + 255) / 256), 256, 0, stream>>>(x, xb, nx);

  const int foldBlocks = (H_DIM * D_DIM + 255) / 256;
  fold_lora_kernel<<<foldBlocks, 256, 0, stream>>>(W1, A1, B1, W1eff, H_DIM, D_DIM);
  fold_lora_kernel<<<foldBlocks, 256, 0, stream>>>(W2, A2, B2, W2eff, D_DIM, H_DIM);

  // GEMM1: 99 rbands x 24 cols; per XCD 13 rbands, rband-fast -> grid 24*13*8
  gemm_kernel<true, bf16_t, 1, 33792><<<2496, 256, 0, stream>>>(
      xb, W1eff, b1, hbuf, M_ROWS, H_DIM, D_DIM);
  // GEMM2: 99 rbands x 6 cols; two 4-XCD groups x 3 cols, col-fast -> 25*3*8
  gemm_kernel<false, float, 2, 32768><<<600, 256, 0, stream>>>(
      hbuf, W2eff, b2, out, M_ROWS, D_DIM, H_DIM);
}